// Round 3
// baseline (758.209 us; speedup 1.0000x reference)
//
#include <hip/hip_runtime.h>
#include <cstdint>
#include <cstddef>

#define NN  20000
#define EE  640000
#define KIN 4096
#define HD  512
#define NC  10
#define CAP 128   // per-node CSR capacity; deg ~ Poisson(32), max ~60 — 128 is safe

typedef __attribute__((ext_vector_type(8))) short short8;
typedef __attribute__((ext_vector_type(4))) float f32x4;

__device__ __forceinline__ unsigned short f2b(float f) {
  union { float f; unsigned int u; } v; v.f = f;
  unsigned int r = v.u + 0x7fffu + ((v.u >> 16) & 1u);
  return (unsigned short)(r >> 16);
}

// Single-instruction packed fp32->bf16 (RNE). lo -> low 16 bits, hi -> high 16 bits.
__device__ __forceinline__ unsigned int cvt2(float lo, float hi) {
  unsigned int r;
  asm("v_cvt_pk_bf16_f32 %0, %1, %2" : "=v"(r) : "v"(lo), "v"(hi));
  return r;
}

__device__ __forceinline__ void gload16(const void* g, void* l) {
  __builtin_amdgcn_global_load_lds(
      (const __attribute__((address_space(1))) unsigned int*)g,
      (__attribute__((address_space(3))) unsigned int*)l, 16, 0, 0);
}

// ---------------- CSR build: degree count + capacity scatter in one pass ----------------
__global__ __launch_bounds__(256) void scatk(const int* __restrict__ src, const int* __restrict__ dst,
                                             int* __restrict__ deg, int* __restrict__ csr) {
  int e = blockIdx.x * 256 + threadIdx.x;
  if (e < EE) {
    int d = dst[e];
    int p = atomicAdd(&deg[d], 1);
    csr[d * CAP + p] = src[e];
  }
}

__global__ __launch_bounds__(256) void dinvk(const int* __restrict__ deg, float* __restrict__ dinv) {
  int i = blockIdx.x * 256 + threadIdx.x;
  if (i < NN) dinv[i] = 1.0f / sqrtf((float)(deg[i] + 1));  // +1 self loop
}

// ---------------- W1 transpose + bf16 convert: W1t[h][k] ----------------
__global__ __launch_bounds__(256) void transk(const float* __restrict__ W1, unsigned short* __restrict__ w1t) {
  __shared__ float tile[32][33];
  int h0 = blockIdx.x * 32;   // 16 blocks
  int k0 = blockIdx.y * 32;   // 128 blocks
  int tx = threadIdx.x & 31, ty = threadIdx.x >> 5;  // ty 0..7
#pragma unroll
  for (int r = 0; r < 4; ++r) {
    int k = ty * 4 + r;
    tile[k][tx] = W1[(size_t)(k0 + k) * HD + h0 + tx];
  }
  __syncthreads();
#pragma unroll
  for (int r = 0; r < 4; ++r) {
    int h = ty * 4 + r;
    w1t[(size_t)(h0 + h) * KIN + k0 + tx] = f2b(tile[tx][h]);
  }
}

// ---------------- GEMM1: h1b = bf16(x @ W1) ----------------
// Tile M128 x N128, BK=64, 256 threads = 4 waves (2x2 of 64x64 each). Grid 157*4 = 628
// blocks with XCD-bijective swizzle (keeps A panel + w1t L2-resident per XCD).
// v3: T3-minimum 2-phase pipeline. Double-buffered As/Bs (64 KB LDS -> 2 blocks/CU).
// ONE barrier per K-step: prefetch A(t+1)->regs and B(t+1)->LDS-DMA at loop top,
// compute(t) hides the load latency, then cvt+ds_write A(t+1) (compiler inserts the
// counted vmcnt wait) and __syncthreads(). Nothing in flight crosses the barrier, so
// the plain __syncthreads() drain is cheap and race-free.
// LDS swizzle unchanged: granule q (8 bf16) of row r stored at chunk c = q ^ (r&7).
__global__ __launch_bounds__(256) void gemm1(const float* __restrict__ x,
                                             const unsigned short* __restrict__ w1t,
                                             unsigned short* __restrict__ h1b) {
  __shared__ __align__(16) unsigned short As[2][128 * 64];   // 32 KB
  __shared__ __align__(16) unsigned short Bs[2][128 * 64];   // 32 KB
  int t = threadIdx.x;
  int l = t & 63, w = t >> 6;
  int wm = w >> 1, wn = w & 1;

  // XCD-bijective swizzle (m204): nwg=628, q=78, r=4
  int orig = blockIdx.x;
  int xcd = orig & 7, jj = orig >> 3;
  int tile = (xcd < 4 ? xcd * 79 : 316 + (xcd - 4) * 78) + jj;
  int bm = (tile >> 2) * 128;
  int bn = (tile & 3) * 128;

  // A staging: thread handles rows {i*32 + t>>3}, chunk t&7; fetches granule q = chunk ^ (row&7)
  int stRow = t >> 3;                 // 0..31
  int stQ = (t & 7) ^ (stRow & 7);
  const float* ga[4];
#pragma unroll
  for (int i = 0; i < 4; ++i) {
    int m = bm + i * 32 + stRow;
    if (m > NN - 1) m = NN - 1;       // clamp; epilogue masks rows >= NN
    ga[i] = x + (size_t)m * KIN + stQ * 8;
  }

  // B staging via LDS-DMA: instr i covers rows i*32 + w*8 + (l>>3); lane chunk l&7 fetches q = (l&7)^(row&7)
  int rl = l >> 3;
  int cq = (l & 7) ^ rl;
  const unsigned short* gb[4];
  int lBoff[4];
#pragma unroll
  for (int i = 0; i < 4; ++i) {
    int rowB = bn + i * 32 + w * 8 + rl;
    gb[i] = w1t + (size_t)rowB * KIN + cq * 8;
    lBoff[i] = (i * 32 + w * 8) * 64;   // wave-uniform base; DMA appends lane*16B
  }

  // fragment LDS offsets (shorts): row*64 + col0*8; col0 = (l>>4) ^ (row&7), row&7 == l&7
  int col0 = ((l >> 4) ^ (l & 7));
  int fm[4], fn[4];
#pragma unroll
  for (int i = 0; i < 4; ++i) fm[i] = (wm * 64 + i * 16 + (l & 15)) * 64 + col0 * 8;
#pragma unroll
  for (int j = 0; j < 4; ++j) fn[j] = (wn * 64 + j * 16 + (l & 15)) * 64 + col0 * 8;

  f32x4 acc[4][4] = {};
  float4 pa[4][2];

  // ---- prologue: stage K-tile 0 into buffer 0 ----
#pragma unroll
  for (int i = 0; i < 4; ++i) {
    pa[i][0] = *reinterpret_cast<const float4*>(ga[i]);
    pa[i][1] = *reinterpret_cast<const float4*>(ga[i] + 4);
  }
#pragma unroll
  for (int i = 0; i < 4; ++i) gload16(gb[i], &Bs[0][lBoff[i]]);
#pragma unroll
  for (int i = 0; i < 4; ++i) {
    uint4 val;
    val.x = cvt2(pa[i][0].x, pa[i][0].y);
    val.y = cvt2(pa[i][0].z, pa[i][0].w);
    val.z = cvt2(pa[i][1].x, pa[i][1].y);
    val.w = cvt2(pa[i][1].z, pa[i][1].w);
    *reinterpret_cast<uint4*>(&As[0][i * 2048 + 8 * t]) = val;
  }
  __syncthreads();

  for (int tk = 0; tk < 64; ++tk) {
    int cur = tk & 1;
    int k1 = (tk + 1) * 64;
    if (tk < 63) {
      // issue next tile's loads: A -> regs (8 dwordx4), B -> LDS-DMA (4 dwordx4)
#pragma unroll
      for (int i = 0; i < 4; ++i) {
        pa[i][0] = *reinterpret_cast<const float4*>(ga[i] + k1);
        pa[i][1] = *reinterpret_cast<const float4*>(ga[i] + k1 + 4);
      }
#pragma unroll
      for (int i = 0; i < 4; ++i) gload16(gb[i] + k1, &Bs[cur ^ 1][lBoff[i]]);
    }
    // compute current tile — hides the prefetch latency
#pragma unroll
    for (int kk = 0; kk < 2; ++kk) {
      int xr = kk << 5;  // flips granule bit2 (64 bytes)
      short8 af[4], bf[4];
#pragma unroll
      for (int i = 0; i < 4; ++i) af[i] = *reinterpret_cast<const short8*>(&As[cur][0] + (fm[i] ^ xr));
#pragma unroll
      for (int j = 0; j < 4; ++j) bf[j] = *reinterpret_cast<const short8*>(&Bs[cur][0] + (fn[j] ^ xr));
#pragma unroll
      for (int i = 0; i < 4; ++i)
#pragma unroll
        for (int j = 0; j < 4; ++j)
          acc[i][j] = __builtin_amdgcn_mfma_f32_16x16x32_bf16(af[i], bf[j], acc[i][j], 0, 0, 0);
    }
    if (tk < 63) {
      // convert + write A(t+1) into the other buffer (auto counted vmcnt wait on pa)
#pragma unroll
      for (int i = 0; i < 4; ++i) {
        uint4 val;
        val.x = cvt2(pa[i][0].x, pa[i][0].y);
        val.y = cvt2(pa[i][0].z, pa[i][0].w);
        val.z = cvt2(pa[i][1].x, pa[i][1].y);
        val.w = cvt2(pa[i][1].z, pa[i][1].w);
        *reinterpret_cast<uint4*>(&As[cur ^ 1][i * 2048 + 8 * t]) = val;
      }
      __syncthreads();   // vmcnt(0)/lgkm(0) drain is cheap: everything already landed
    }
  }

  int lq = l >> 4;
  bool even = (l & 1) == 0;
#pragma unroll
  for (int i = 0; i < 4; ++i) {
    int row0 = bm + wm * 64 + i * 16 + lq * 4;
#pragma unroll
    for (int j = 0; j < 4; ++j) {
      int col = bn + wn * 64 + j * 16 + (l & 15);
#pragma unroll
      for (int r = 0; r < 4; ++r) {
        float v0 = acc[i][j][r];
        float v1 = __shfl_xor(v0, 1);
        int row = row0 + r;
        if (even && row < NN) {
          *reinterpret_cast<unsigned int*>(h1b + (size_t)row * HD + col) = cvt2(v0, v1);
        }
      }
    }
  }
}

// ---------------- Fused SpMM1 + GEMM2: h2 = relu(Agg(h1)+b1) @ W2 ----------------
__global__ __launch_bounds__(256) void sgk(const unsigned short* __restrict__ h1b, const int* __restrict__ deg,
                                           const int* __restrict__ csr, const float* __restrict__ dinv,
                                           const float* __restrict__ b1, const float* __restrict__ W2,
                                           float* __restrict__ h2) {
  __shared__ int s_idx[CAP];
  __shared__ float s_w[CAP];
  __shared__ float red[4][NC];
  int i = blockIdx.x;
  int c = threadIdx.x;  // column pair 2c, 2c+1
  float di = dinv[i];
  int dg = deg[i];
  if (c < dg) {
    int s = csr[i * CAP + c];
    s_idx[c] = s;
    s_w[c] = dinv[s] * di;
  }
  const unsigned int* h1v = reinterpret_cast<const unsigned int*>(h1b);
  unsigned int su = h1v[(size_t)i * 256 + c];
  float wself = di * di;
  float a0 = __uint_as_float(su << 16) * wself;
  float a1 = __uint_as_float(su & 0xffff0000u) * wself;
  __syncthreads();
#pragma unroll 4
  for (int jj = 0; jj < dg; ++jj) {
    unsigned int u = h1v[(size_t)s_idx[jj] * 256 + c];
    float wgt = s_w[jj];
    a0 += __uint_as_float(u << 16) * wgt;
    a1 += __uint_as_float(u & 0xffff0000u) * wgt;
  }
  float2 bb = reinterpret_cast<const float2*>(b1)[c];
  float zx = fmaxf(a0 + bb.x, 0.f);
  float zy = fmaxf(a1 + bb.y, 0.f);
  // gemm2 part: thread c holds z[2c], z[2c+1]
  const float* w2r = W2 + (size_t)(2 * c) * NC;
  float part[NC];
#pragma unroll
  for (int cc = 0; cc < NC; ++cc) part[cc] = zx * w2r[cc] + zy * w2r[NC + cc];
#pragma unroll
  for (int cc = 0; cc < NC; ++cc) {
#pragma unroll
    for (int m = 1; m < 64; m <<= 1) part[cc] += __shfl_xor(part[cc], m, 64);
  }
  int wv = c >> 6, ln = c & 63;
  if (ln == 0) {
#pragma unroll
    for (int cc = 0; cc < NC; ++cc) red[wv][cc] = part[cc];
  }
  __syncthreads();
  if (c < NC) h2[(size_t)i * NC + c] = red[0][c] + red[1][c] + red[2][c] + red[3][c];
}

// ---------------- SpMM2 + bias + log_softmax ----------------
__global__ __launch_bounds__(64) void spmm2(const float* __restrict__ h2, const int* __restrict__ deg,
                                            const int* __restrict__ csr, const float* __restrict__ dinv,
                                            const float* __restrict__ b2, float* __restrict__ out) {
  int i = blockIdx.x;
  int l = threadIdx.x;
  float di = dinv[i];
  int dg = deg[i];
  float acc[NC] = {};
  for (int e = l; e < dg; e += 64) {
    int s = csr[i * CAP + e];
    float wgt = dinv[s] * di;
    const float2* hp = reinterpret_cast<const float2*>(h2 + (size_t)s * NC);
#pragma unroll
    for (int cc = 0; cc < 5; ++cc) {
      float2 v = hp[cc];
      acc[2 * cc] += v.x * wgt;
      acc[2 * cc + 1] += v.y * wgt;
    }
  }
  if (l == 0) {
    float ws = di * di;
#pragma unroll
    for (int cc = 0; cc < NC; ++cc) acc[cc] += h2[(size_t)i * NC + cc] * ws;
  }
#pragma unroll
  for (int cc = 0; cc < NC; ++cc) {
#pragma unroll
    for (int m = 1; m < 64; m <<= 1) acc[cc] += __shfl_xor(acc[cc], m, 64);
  }
  if (l == 0) {
    float v[NC];
    float mx = -1e30f;
#pragma unroll
    for (int cc = 0; cc < NC; ++cc) {
      v[cc] = acc[cc] + b2[cc];
      mx = fmaxf(mx, v[cc]);
    }
    float s = 0.f;
#pragma unroll
    for (int cc = 0; cc < NC; ++cc) s += expf(v[cc] - mx);
    float lse = mx + logf(s);
#pragma unroll
    for (int cc = 0; cc < NC; ++cc) out[(size_t)i * NC + cc] = v[cc] - lse;
  }
}

extern "C" void kernel_launch(void* const* d_in, const int* in_sizes, int n_in,
                              void* d_out, int out_size, void* d_ws, size_t ws_size,
                              hipStream_t stream) {
  (void)in_sizes; (void)n_in; (void)out_size; (void)ws_size;
  const float* x  = (const float*)d_in[0];
  const int*   ei = (const int*)d_in[1];
  const float* W1 = (const float*)d_in[2];
  const float* b1 = (const float*)d_in[3];
  const float* W2 = (const float*)d_in[4];
  const float* b2 = (const float*)d_in[5];
  float* out = (float*)d_out;
  char* ws = (char*)d_ws;

  unsigned short* w1t = (unsigned short*)(ws);              //  4,194,304 B
  unsigned short* h1b = (unsigned short*)(ws + 4194304);    // 20,480,000 B
  float* h2   = (float*)(ws + 24674304);                    //    800,000 B
  int*   deg  = (int*)(ws + 25474304);                      //     80,000 B
  float* dinv = (float*)(ws + 25554304);                    //     80,000 B
  int*   csr  = (int*)(ws + 25634304);                      // 10,240,000 B -> end 35,874,304

  const int* srcp = ei;
  const int* dstp = ei + EE;

  hipMemsetAsync(deg, 0, NN * sizeof(int), stream);
  scatk<<<(EE + 255) / 256, 256, 0, stream>>>(srcp, dstp, deg, csr);
  dinvk<<<(NN + 255) / 256, 256, 0, stream>>>(deg, dinv);
  transk<<<dim3(16, 128), 256, 0, stream>>>(W1, w1t);
  gemm1<<<157 * 4, 256, 0, stream>>>(x, w1t, h1b);
  sgk<<<NN, 256, 0, stream>>>(h1b, deg, csr, dinv, b1, W2, h2);
  spmm2<<<NN, 64, 0, stream>>>(h2, deg, csr, dinv, b2, out);
}

// Round 4
// 706.305 us; speedup vs baseline: 1.0735x; 1.0735x over previous
//
#include <hip/hip_runtime.h>
#include <cstdint>
#include <cstddef>

#define NN  20000
#define EE  640000
#define KIN 4096
#define HD  512
#define NC  10
#define CAP 128   // per-node CSR capacity; deg ~ Poisson(32), max ~60 — 128 is safe

typedef __attribute__((ext_vector_type(8))) short short8;
typedef __attribute__((ext_vector_type(4))) float f32x4;

__device__ __forceinline__ unsigned short f2b(float f) {
  union { float f; unsigned int u; } v; v.f = f;
  unsigned int r = v.u + 0x7fffu + ((v.u >> 16) & 1u);
  return (unsigned short)(r >> 16);
}

// Single-instruction packed fp32->bf16 (RNE). lo -> low 16 bits, hi -> high 16 bits.
__device__ __forceinline__ unsigned int cvt2(float lo, float hi) {
  unsigned int r;
  asm("v_cvt_pk_bf16_f32 %0, %1, %2" : "=v"(r) : "v"(lo), "v"(hi));
  return r;
}

__device__ __forceinline__ void gload16(const void* g, void* l) {
  __builtin_amdgcn_global_load_lds(
      (const __attribute__((address_space(1))) unsigned int*)g,
      (__attribute__((address_space(3))) unsigned int*)l, 16, 0, 0);
}

__device__ __forceinline__ float bflo(unsigned int u) { return __uint_as_float(u << 16); }
__device__ __forceinline__ float bfhi(unsigned int u) { return __uint_as_float(u & 0xffff0000u); }

// ---------------- CSR build: degree count + capacity scatter in one pass ----------------
__global__ __launch_bounds__(256) void scatk(const int* __restrict__ src, const int* __restrict__ dst,
                                             int* __restrict__ deg, int* __restrict__ csr) {
  int e = blockIdx.x * 256 + threadIdx.x;
  if (e < EE) {
    int d = dst[e];
    int p = atomicAdd(&deg[d], 1);
    csr[d * CAP + p] = src[e];
  }
}

__global__ __launch_bounds__(256) void dinvk(const int* __restrict__ deg, float* __restrict__ dinv) {
  int i = blockIdx.x * 256 + threadIdx.x;
  if (i < NN) dinv[i] = 1.0f / sqrtf((float)(deg[i] + 1));  // +1 self loop
}

// ---------------- W1 transpose + bf16 convert: W1t[h][k] ----------------
__global__ __launch_bounds__(256) void transk(const float* __restrict__ W1, unsigned short* __restrict__ w1t) {
  __shared__ float tile[32][33];
  int h0 = blockIdx.x * 32;   // 16 blocks
  int k0 = blockIdx.y * 32;   // 128 blocks
  int tx = threadIdx.x & 31, ty = threadIdx.x >> 5;  // ty 0..7
#pragma unroll
  for (int r = 0; r < 4; ++r) {
    int k = ty * 4 + r;
    tile[k][tx] = W1[(size_t)(k0 + k) * HD + h0 + tx];
  }
  __syncthreads();
#pragma unroll
  for (int r = 0; r < 4; ++r) {
    int h = ty * 4 + r;
    w1t[(size_t)(h0 + h) * KIN + k0 + tx] = f2b(tile[tx][h]);
  }
}

// ---------------- GEMM1: h1b = bf16(x @ W1) ----------------
// Tile M128 x N128, BK=64, 256 threads = 4 waves (2x2 of 64x64 each). Grid 157*4 = 628
// blocks with XCD-bijective swizzle (keeps A panel + w1t L2-resident per XCD).
// v4: latency-hiding pipeline at 3 blocks/CU. Single-buffer As (16 KB; its "second
// buffer" is the pa registers) + double-buffer Bs (32 KB) = 48 KB LDS.
// Per iter: issue A(t+1)->regs + B(t+1)->LDS-DMA[cur^1], sched_barrier pin, compute(t),
// sched_barrier pin (stops the compiler hoisting the pa vmcnt-wait above the MFMAs —
// round-3's regression), raw s_barrier (waves done READING As; MFMA issue implies
// ds_read retirement so no drain needed), cvt+write As(t+1), __syncthreads (full
// drain: As writes + B DMA visible; DMA had compute+cvt time to land).
// LDS swizzle unchanged: granule q (8 bf16) of row r stored at chunk c = q ^ (r&7).
__global__ __launch_bounds__(256) void gemm1(const float* __restrict__ x,
                                             const unsigned short* __restrict__ w1t,
                                             unsigned short* __restrict__ h1b) {
  __shared__ __align__(16) unsigned short As[128 * 64];      // 16 KB
  __shared__ __align__(16) unsigned short Bs[2][128 * 64];   // 32 KB
  int t = threadIdx.x;
  int l = t & 63, w = t >> 6;
  int wm = w >> 1, wn = w & 1;

  // XCD-bijective swizzle (m204): nwg=628, q=78, r=4
  int orig = blockIdx.x;
  int xcd = orig & 7, jj = orig >> 3;
  int tile = (xcd < 4 ? xcd * 79 : 316 + (xcd - 4) * 78) + jj;
  int bm = (tile >> 2) * 128;
  int bn = (tile & 3) * 128;

  // A staging: thread handles rows {i*32 + t>>3}, chunk t&7; fetches granule q = chunk ^ (row&7)
  int stRow = t >> 3;                 // 0..31
  int stQ = (t & 7) ^ (stRow & 7);
  const float* ga[4];
#pragma unroll
  for (int i = 0; i < 4; ++i) {
    int m = bm + i * 32 + stRow;
    if (m > NN - 1) m = NN - 1;       // clamp; epilogue masks rows >= NN
    ga[i] = x + (size_t)m * KIN + stQ * 8;
  }

  // B staging via LDS-DMA: instr i covers rows i*32 + w*8 + (l>>3); lane chunk l&7 fetches q = (l&7)^(row&7)
  int rl = l >> 3;
  int cq = (l & 7) ^ rl;
  const unsigned short* gb[4];
  int lBoff[4];
#pragma unroll
  for (int i = 0; i < 4; ++i) {
    int rowB = bn + i * 32 + w * 8 + rl;
    gb[i] = w1t + (size_t)rowB * KIN + cq * 8;
    lBoff[i] = (i * 32 + w * 8) * 64;   // wave-uniform base; DMA appends lane*16B
  }

  // fragment LDS offsets (shorts): row*64 + col0*8; col0 = (l>>4) ^ (row&7), row&7 == l&7
  int col0 = ((l >> 4) ^ (l & 7));
  int fm[4], fn[4];
#pragma unroll
  for (int i = 0; i < 4; ++i) fm[i] = (wm * 64 + i * 16 + (l & 15)) * 64 + col0 * 8;
#pragma unroll
  for (int j = 0; j < 4; ++j) fn[j] = (wn * 64 + j * 16 + (l & 15)) * 64 + col0 * 8;

  f32x4 acc[4][4] = {};
  float4 pa[4][2];

  // ---- prologue: stage K-tile 0 (A via regs->As, B via DMA->Bs[0]) ----
#pragma unroll
  for (int i = 0; i < 4; ++i) {
    pa[i][0] = *reinterpret_cast<const float4*>(ga[i]);
    pa[i][1] = *reinterpret_cast<const float4*>(ga[i] + 4);
  }
#pragma unroll
  for (int i = 0; i < 4; ++i) gload16(gb[i], &Bs[0][lBoff[i]]);
#pragma unroll
  for (int i = 0; i < 4; ++i) {
    uint4 val;
    val.x = cvt2(pa[i][0].x, pa[i][0].y);
    val.y = cvt2(pa[i][0].z, pa[i][0].w);
    val.z = cvt2(pa[i][1].x, pa[i][1].y);
    val.w = cvt2(pa[i][1].z, pa[i][1].w);
    *reinterpret_cast<uint4*>(&As[i * 2048 + 8 * t]) = val;
  }
  __syncthreads();   // drains A writes + B DMA for tile 0

  for (int tk = 0; tk < 64; ++tk) {
    int cur = tk & 1;
    if (tk < 63) {
      int k1 = (tk + 1) * 64;
      // issue next tile's loads: A -> regs (8 dwordx4), B -> LDS-DMA into other buffer
#pragma unroll
      for (int i = 0; i < 4; ++i) {
        pa[i][0] = *reinterpret_cast<const float4*>(ga[i] + k1);
        pa[i][1] = *reinterpret_cast<const float4*>(ga[i] + k1 + 4);
      }
#pragma unroll
      for (int i = 0; i < 4; ++i) gload16(gb[i] + k1, &Bs[cur ^ 1][lBoff[i]]);
    }
    __builtin_amdgcn_sched_barrier(0);   // loads issued BEFORE compute, never sunk below
    // compute current tile from As, Bs[cur] — hides the prefetch latency
#pragma unroll
    for (int kk = 0; kk < 2; ++kk) {
      int xr = kk << 5;  // flips granule bit2 (64 bytes)
      short8 af[4], bf[4];
#pragma unroll
      for (int i = 0; i < 4; ++i) af[i] = *reinterpret_cast<const short8*>(As + (fm[i] ^ xr));
#pragma unroll
      for (int j = 0; j < 4; ++j) bf[j] = *reinterpret_cast<const short8*>(&Bs[cur][0] + (fn[j] ^ xr));
#pragma unroll
      for (int i = 0; i < 4; ++i)
#pragma unroll
        for (int j = 0; j < 4; ++j)
          acc[i][j] = __builtin_amdgcn_mfma_f32_16x16x32_bf16(af[i], bf[j], acc[i][j], 0, 0, 0);
    }
    __builtin_amdgcn_sched_barrier(0);   // cvt/vmcnt-wait may NOT hoist above MFMAs
    if (tk < 63) {
      __builtin_amdgcn_s_barrier();      // all waves finished READING As (no drain needed:
                                         // MFMA issue implies its ds_reads retired)
      __builtin_amdgcn_sched_barrier(0); // ds_write may not float above the barrier
#pragma unroll
      for (int i = 0; i < 4; ++i) {      // compiler inserts counted vmcnt wait on pa here
        uint4 val;
        val.x = cvt2(pa[i][0].x, pa[i][0].y);
        val.y = cvt2(pa[i][0].z, pa[i][0].w);
        val.z = cvt2(pa[i][1].x, pa[i][1].y);
        val.w = cvt2(pa[i][1].z, pa[i][1].w);
        *reinterpret_cast<uint4*>(&As[i * 2048 + 8 * t]) = val;
      }
      __syncthreads();                   // As writes + B DMA visible for next iter
    }
  }

  int lq = l >> 4;
  bool even = (l & 1) == 0;
#pragma unroll
  for (int i = 0; i < 4; ++i) {
    int row0 = bm + wm * 64 + i * 16 + lq * 4;
#pragma unroll
    for (int j = 0; j < 4; ++j) {
      int col = bn + wn * 64 + j * 16 + (l & 15);
#pragma unroll
      for (int r = 0; r < 4; ++r) {
        float v0 = acc[i][j][r];
        float v1 = __shfl_xor(v0, 1);
        int row = row0 + r;
        if (even && row < NN) {
          *reinterpret_cast<unsigned int*>(h1b + (size_t)row * HD + col) = cvt2(v0, v1);
        }
      }
    }
  }
}

// ---------------- Fused SpMM1 + GEMM2: h2 = relu(Agg(h1)+b1) @ W2 ----------------
// v2: 128 threads/block, thread c owns columns 4c..4c+3 -> one 8B uint2 load per
// neighbor row (coalescing sweet spot), half the reduce cost (2 waves not 4).
__global__ __launch_bounds__(128) void sgk(const unsigned short* __restrict__ h1b, const int* __restrict__ deg,
                                           const int* __restrict__ csr, const float* __restrict__ dinv,
                                           const float* __restrict__ b1, const float* __restrict__ W2,
                                           float* __restrict__ h2) {
  __shared__ int s_idx[CAP];
  __shared__ float s_w[CAP];
  __shared__ float red[2][NC];
  int i = blockIdx.x;
  int c = threadIdx.x;  // columns 4c..4c+3
  float di = dinv[i];
  int dg = deg[i];
  if (c < dg) {
    int s = csr[i * CAP + c];
    s_idx[c] = s;
    s_w[c] = dinv[s] * di;
  }
  const uint2* h1v = reinterpret_cast<const uint2*>(h1b);  // row = 128 uint2
  uint2 su = h1v[(size_t)i * 128 + c];
  float wself = di * di;
  float a0 = bflo(su.x) * wself, a1 = bfhi(su.x) * wself;
  float a2 = bflo(su.y) * wself, a3 = bfhi(su.y) * wself;
  __syncthreads();
#pragma unroll 4
  for (int jj = 0; jj < dg; ++jj) {
    uint2 u = h1v[(size_t)s_idx[jj] * 128 + c];
    float wgt = s_w[jj];
    a0 += bflo(u.x) * wgt;
    a1 += bfhi(u.x) * wgt;
    a2 += bflo(u.y) * wgt;
    a3 += bfhi(u.y) * wgt;
  }
  float4 bb = reinterpret_cast<const float4*>(b1)[c];
  float z0 = fmaxf(a0 + bb.x, 0.f);
  float z1 = fmaxf(a1 + bb.y, 0.f);
  float z2 = fmaxf(a2 + bb.z, 0.f);
  float z3 = fmaxf(a3 + bb.w, 0.f);
  // gemm2 part: thread c holds z[4c..4c+3] -> rows 4c..4c+3 of W2
  const float* w2r = W2 + (size_t)(4 * c) * NC;
  float part[NC];
#pragma unroll
  for (int cc = 0; cc < NC; ++cc)
    part[cc] = z0 * w2r[cc] + z1 * w2r[NC + cc] + z2 * w2r[2 * NC + cc] + z3 * w2r[3 * NC + cc];
#pragma unroll
  for (int cc = 0; cc < NC; ++cc) {
#pragma unroll
    for (int m = 1; m < 64; m <<= 1) part[cc] += __shfl_xor(part[cc], m, 64);
  }
  int wv = c >> 6, ln = c & 63;
  if (ln == 0) {
#pragma unroll
    for (int cc = 0; cc < NC; ++cc) red[wv][cc] = part[cc];
  }
  __syncthreads();
  if (c < NC) h2[(size_t)i * NC + c] = red[0][c] + red[1][c];
}

// ---------------- SpMM2 + bias + log_softmax ----------------
__global__ __launch_bounds__(64) void spmm2(const float* __restrict__ h2, const int* __restrict__ deg,
                                            const int* __restrict__ csr, const float* __restrict__ dinv,
                                            const float* __restrict__ b2, float* __restrict__ out) {
  int i = blockIdx.x;
  int l = threadIdx.x;
  float di = dinv[i];
  int dg = deg[i];
  float acc[NC] = {};
  for (int e = l; e < dg; e += 64) {
    int s = csr[i * CAP + e];
    float wgt = dinv[s] * di;
    const float2* hp = reinterpret_cast<const float2*>(h2 + (size_t)s * NC);
#pragma unroll
    for (int cc = 0; cc < 5; ++cc) {
      float2 v = hp[cc];
      acc[2 * cc] += v.x * wgt;
      acc[2 * cc + 1] += v.y * wgt;
    }
  }
  if (l == 0) {
    float ws = di * di;
#pragma unroll
    for (int cc = 0; cc < NC; ++cc) acc[cc] += h2[(size_t)i * NC + cc] * ws;
  }
#pragma unroll
  for (int cc = 0; cc < NC; ++cc) {
#pragma unroll
    for (int m = 1; m < 64; m <<= 1) acc[cc] += __shfl_xor(acc[cc], m, 64);
  }
  if (l == 0) {
    float v[NC];
    float mx = -1e30f;
#pragma unroll
    for (int cc = 0; cc < NC; ++cc) {
      v[cc] = acc[cc] + b2[cc];
      mx = fmaxf(mx, v[cc]);
    }
    float s = 0.f;
#pragma unroll
    for (int cc = 0; cc < NC; ++cc) s += expf(v[cc] - mx);
    float lse = mx + logf(s);
#pragma unroll
    for (int cc = 0; cc < NC; ++cc) out[(size_t)i * NC + cc] = v[cc] - lse;
  }
}

extern "C" void kernel_launch(void* const* d_in, const int* in_sizes, int n_in,
                              void* d_out, int out_size, void* d_ws, size_t ws_size,
                              hipStream_t stream) {
  (void)in_sizes; (void)n_in; (void)out_size; (void)ws_size;
  const float* x  = (const float*)d_in[0];
  const int*   ei = (const int*)d_in[1];
  const float* W1 = (const float*)d_in[2];
  const float* b1 = (const float*)d_in[3];
  const float* W2 = (const float*)d_in[4];
  const float* b2 = (const float*)d_in[5];
  float* out = (float*)d_out;
  char* ws = (char*)d_ws;

  unsigned short* w1t = (unsigned short*)(ws);              //  4,194,304 B
  unsigned short* h1b = (unsigned short*)(ws + 4194304);    // 20,480,000 B
  float* h2   = (float*)(ws + 24674304);                    //    800,000 B
  int*   deg  = (int*)(ws + 25474304);                      //     80,000 B
  float* dinv = (float*)(ws + 25554304);                    //     80,000 B
  int*   csr  = (int*)(ws + 25634304);                      // 10,240,000 B -> end 35,874,304

  const int* srcp = ei;
  const int* dstp = ei + EE;

  hipMemsetAsync(deg, 0, NN * sizeof(int), stream);
  scatk<<<(EE + 255) / 256, 256, 0, stream>>>(srcp, dstp, deg, csr);
  dinvk<<<(NN + 255) / 256, 256, 0, stream>>>(deg, dinv);
  transk<<<dim3(16, 128), 256, 0, stream>>>(W1, w1t);
  gemm1<<<157 * 4, 256, 0, stream>>>(x, w1t, h1b);
  sgk<<<NN, 128, 0, stream>>>(h1b, deg, csr, dinv, b1, W2, h2);
  spmm2<<<NN, 64, 0, stream>>>(h2, deg, csr, dinv, b2, out);
}

// Round 5
// 666.812 us; speedup vs baseline: 1.1371x; 1.0592x over previous
//
#include <hip/hip_runtime.h>
#include <cstdint>
#include <cstddef>

#define NN  20000
#define EE  640000
#define KIN 4096
#define HD  512
#define NC  10
#define CAP 128   // per-node CSR capacity; deg ~ Poisson(32), max ~60 — 128 is safe

typedef __attribute__((ext_vector_type(8))) short short8;
typedef __attribute__((ext_vector_type(4))) float f32x4;

__device__ __forceinline__ unsigned short f2b(float f) {
  union { float f; unsigned int u; } v; v.f = f;
  unsigned int r = v.u + 0x7fffu + ((v.u >> 16) & 1u);
  return (unsigned short)(r >> 16);
}

// Single-instruction packed fp32->bf16 (RNE). lo -> low 16 bits, hi -> high 16 bits.
__device__ __forceinline__ unsigned int cvt2(float lo, float hi) {
  unsigned int r;
  asm("v_cvt_pk_bf16_f32 %0, %1, %2" : "=v"(r) : "v"(lo), "v"(hi));
  return r;
}

__device__ __forceinline__ void gload16(const void* g, void* l) {
  __builtin_amdgcn_global_load_lds(
      (const __attribute__((address_space(1))) unsigned int*)g,
      (__attribute__((address_space(3))) unsigned int*)l, 16, 0, 0);
}

__device__ __forceinline__ float bflo(unsigned int u) { return __uint_as_float(u << 16); }
__device__ __forceinline__ float bfhi(unsigned int u) { return __uint_as_float(u & 0xffff0000u); }

// ---------------- CSR build: degree count + capacity scatter in one pass ----------------
__global__ __launch_bounds__(256) void scatk(const int* __restrict__ src, const int* __restrict__ dst,
                                             int* __restrict__ deg, int* __restrict__ csr) {
  int e = blockIdx.x * 256 + threadIdx.x;
  if (e < EE) {
    int d = dst[e];
    int p = atomicAdd(&deg[d], 1);
    csr[d * CAP + p] = src[e];
  }
}

__global__ __launch_bounds__(256) void dinvk(const int* __restrict__ deg, float* __restrict__ dinv) {
  int i = blockIdx.x * 256 + threadIdx.x;
  if (i < NN) dinv[i] = 1.0f / sqrtf((float)(deg[i] + 1));  // +1 self loop
}

// ---------------- W1 transpose + bf16 convert: W1t[h][k] ----------------
__global__ __launch_bounds__(256) void transk(const float* __restrict__ W1, unsigned short* __restrict__ w1t) {
  __shared__ float tile[32][33];
  int h0 = blockIdx.x * 32;   // 16 blocks
  int k0 = blockIdx.y * 32;   // 128 blocks
  int tx = threadIdx.x & 31, ty = threadIdx.x >> 5;  // ty 0..7
#pragma unroll
  for (int r = 0; r < 4; ++r) {
    int k = ty * 4 + r;
    tile[k][tx] = W1[(size_t)(k0 + k) * HD + h0 + tx];
  }
  __syncthreads();
#pragma unroll
  for (int r = 0; r < 4; ++r) {
    int h = ty * 4 + r;
    w1t[(size_t)(h0 + h) * KIN + k0 + tx] = f2b(tile[tx][h]);
  }
}

// ---------------- GEMM1: h1b = bf16(x @ W1) ----------------
// v5: occupancy-first. Tile M64 x N128, BK=64, 256 threads = 4 waves (2x2 of 32x64).
// Grid 314*4 = 1256 blocks (= 8*157, clean XCD-bijective swizzle) -> 4.9 blocks/CU,
// ~19.6 waves/CU (2x round-4). LDS 24 KB -> up to 6 resident. Loop is the PROVEN
// round-1 2-barrier structure — no source-level pipelining (m131-m140: compiler
// schedules this fine; rounds 3/4 confirmed pinning/dbuf regress). Latency is hidden
// by inter-block TLP (m114 implicit overlap). XCD swizzle keeps the 4 N-tiles +
// consecutive M-panels of one XCD co-located -> A read ~once from HBM (FETCH ~205MB).
// A staged fp32->bf16 via v_cvt_pk_bf16_f32, B staged via global_load_lds.
// LDS swizzle: granule q (8 bf16) of row r stored at chunk c = q ^ (r&7).
__global__ __launch_bounds__(256) void gemm1(const float* __restrict__ x,
                                             const unsigned short* __restrict__ w1t,
                                             unsigned short* __restrict__ h1b) {
  __shared__ __align__(16) unsigned short As[64 * 64];    //  8 KB
  __shared__ __align__(16) unsigned short Bs[128 * 64];   // 16 KB
  int t = threadIdx.x;
  int l = t & 63, w = t >> 6;
  int wm = w >> 1, wn = w & 1;

  // XCD-bijective swizzle: nwg = 1256 = 8*157. Consecutive g on one XCD are
  // consecutive (m,n) pairs m-major -> panel locality per XCD L2.
  int orig = blockIdx.x;
  int g = (orig & 7) * 157 + (orig >> 3);
  int bm = (g >> 2) * 64;
  int bn = (g & 3) * 128;

  // A staging: thread handles row t>>3 (0..31), chunk t&7; fetches granule q = chunk ^ (row&7)
  int stRow = t >> 3;                 // 0..31
  int stQ = (t & 7) ^ (stRow & 7);
  const float* ga[2];
#pragma unroll
  for (int i = 0; i < 2; ++i) {
    int m = bm + i * 32 + stRow;
    if (m > NN - 1) m = NN - 1;       // clamp; epilogue masks rows >= NN
    ga[i] = x + (size_t)m * KIN + stQ * 8;
  }

  // B staging via LDS-DMA: instr i covers rows i*32 + w*8 + (l>>3); lane chunk l&7 fetches q = (l&7)^(row&7)
  int rl = l >> 3;
  int cq = (l & 7) ^ rl;
  const unsigned short* gb[4];
  unsigned short* lB[4];
#pragma unroll
  for (int i = 0; i < 4; ++i) {
    int rowB = bn + i * 32 + w * 8 + rl;
    gb[i] = w1t + (size_t)rowB * KIN + cq * 8;
    lB[i] = Bs + (i * 32 + w * 8) * 64;   // wave-uniform base; DMA appends lane*16B
  }

  // fragment LDS offsets (shorts): row*64 + col0*8; col0 = (l>>4) ^ (row&7), row&7 == l&7
  int col0 = ((l >> 4) ^ (l & 7));
  int fm[2], fn[4];
#pragma unroll
  for (int i = 0; i < 2; ++i) fm[i] = (wm * 32 + i * 16 + (l & 15)) * 64 + col0 * 8;
#pragma unroll
  for (int j = 0; j < 4; ++j) fn[j] = (wn * 64 + j * 16 + (l & 15)) * 64 + col0 * 8;

  f32x4 acc[2][4] = {};

  for (int kt = 0; kt < KIN / 64; ++kt) {
    int k0 = kt * 64;
    __syncthreads();
#pragma unroll
    for (int i = 0; i < 4; ++i) gload16(gb[i] + k0, lB[i]);
#pragma unroll
    for (int i = 0; i < 2; ++i) {
      float4 a0 = *reinterpret_cast<const float4*>(ga[i] + k0);
      float4 a1 = *reinterpret_cast<const float4*>(ga[i] + k0 + 4);
      uint4 val;
      val.x = cvt2(a0.x, a0.y);
      val.y = cvt2(a0.z, a0.w);
      val.z = cvt2(a1.x, a1.y);
      val.w = cvt2(a1.z, a1.w);
      *reinterpret_cast<uint4*>(As + i * 2048 + 8 * t) = val;
    }
    __syncthreads();
#pragma unroll
    for (int kk = 0; kk < 2; ++kk) {
      int xr = kk << 5;  // flips granule bit2 (64 bytes)
      short8 af[2], bf[4];
#pragma unroll
      for (int i = 0; i < 2; ++i) af[i] = *reinterpret_cast<const short8*>(As + (fm[i] ^ xr));
#pragma unroll
      for (int j = 0; j < 4; ++j) bf[j] = *reinterpret_cast<const short8*>(Bs + (fn[j] ^ xr));
#pragma unroll
      for (int i = 0; i < 2; ++i)
#pragma unroll
        for (int j = 0; j < 4; ++j)
          acc[i][j] = __builtin_amdgcn_mfma_f32_16x16x32_bf16(af[i], bf[j], acc[i][j], 0, 0, 0);
    }
  }

  int lq = l >> 4;
  bool even = (l & 1) == 0;
#pragma unroll
  for (int i = 0; i < 2; ++i) {
    int row0 = bm + wm * 32 + i * 16 + lq * 4;
#pragma unroll
    for (int j = 0; j < 4; ++j) {
      int col = bn + wn * 64 + j * 16 + (l & 15);
#pragma unroll
      for (int r = 0; r < 4; ++r) {
        float v0 = acc[i][j][r];
        float v1 = __shfl_xor(v0, 1);
        int row = row0 + r;
        if (even && row < NN) {
          *reinterpret_cast<unsigned int*>(h1b + (size_t)row * HD + col) = cvt2(v0, v1);
        }
      }
    }
  }
}

// ---------------- Fused SpMM1 + GEMM2: h2 = relu(Agg(h1)+b1) @ W2 ----------------
// v2: 128 threads/block, thread c owns columns 4c..4c+3 -> one 8B uint2 load per
// neighbor row (coalescing sweet spot), half the reduce cost (2 waves not 4).
__global__ __launch_bounds__(128) void sgk(const unsigned short* __restrict__ h1b, const int* __restrict__ deg,
                                           const int* __restrict__ csr, const float* __restrict__ dinv,
                                           const float* __restrict__ b1, const float* __restrict__ W2,
                                           float* __restrict__ h2) {
  __shared__ int s_idx[CAP];
  __shared__ float s_w[CAP];
  __shared__ float red[2][NC];
  int i = blockIdx.x;
  int c = threadIdx.x;  // columns 4c..4c+3
  float di = dinv[i];
  int dg = deg[i];
  if (c < dg) {
    int s = csr[i * CAP + c];
    s_idx[c] = s;
    s_w[c] = dinv[s] * di;
  }
  const uint2* h1v = reinterpret_cast<const uint2*>(h1b);  // row = 128 uint2
  uint2 su = h1v[(size_t)i * 128 + c];
  float wself = di * di;
  float a0 = bflo(su.x) * wself, a1 = bfhi(su.x) * wself;
  float a2 = bflo(su.y) * wself, a3 = bfhi(su.y) * wself;
  __syncthreads();
#pragma unroll 4
  for (int jj = 0; jj < dg; ++jj) {
    uint2 u = h1v[(size_t)s_idx[jj] * 128 + c];
    float wgt = s_w[jj];
    a0 += bflo(u.x) * wgt;
    a1 += bfhi(u.x) * wgt;
    a2 += bflo(u.y) * wgt;
    a3 += bfhi(u.y) * wgt;
  }
  float4 bb = reinterpret_cast<const float4*>(b1)[c];
  float z0 = fmaxf(a0 + bb.x, 0.f);
  float z1 = fmaxf(a1 + bb.y, 0.f);
  float z2 = fmaxf(a2 + bb.z, 0.f);
  float z3 = fmaxf(a3 + bb.w, 0.f);
  // gemm2 part: thread c holds z[4c..4c+3] -> rows 4c..4c+3 of W2
  const float* w2r = W2 + (size_t)(4 * c) * NC;
  float part[NC];
#pragma unroll
  for (int cc = 0; cc < NC; ++cc)
    part[cc] = z0 * w2r[cc] + z1 * w2r[NC + cc] + z2 * w2r[2 * NC + cc] + z3 * w2r[3 * NC + cc];
#pragma unroll
  for (int cc = 0; cc < NC; ++cc) {
#pragma unroll
    for (int m = 1; m < 64; m <<= 1) part[cc] += __shfl_xor(part[cc], m, 64);
  }
  int wv = c >> 6, ln = c & 63;
  if (ln == 0) {
#pragma unroll
    for (int cc = 0; cc < NC; ++cc) red[wv][cc] = part[cc];
  }
  __syncthreads();
  if (c < NC) h2[(size_t)i * NC + c] = red[0][c] + red[1][c];
}

// ---------------- SpMM2 + bias + log_softmax ----------------
__global__ __launch_bounds__(64) void spmm2(const float* __restrict__ h2, const int* __restrict__ deg,
                                            const int* __restrict__ csr, const float* __restrict__ dinv,
                                            const float* __restrict__ b2, float* __restrict__ out) {
  int i = blockIdx.x;
  int l = threadIdx.x;
  float di = dinv[i];
  int dg = deg[i];
  float acc[NC] = {};
  for (int e = l; e < dg; e += 64) {
    int s = csr[i * CAP + e];
    float wgt = dinv[s] * di;
    const float2* hp = reinterpret_cast<const float2*>(h2 + (size_t)s * NC);
#pragma unroll
    for (int cc = 0; cc < 5; ++cc) {
      float2 v = hp[cc];
      acc[2 * cc] += v.x * wgt;
      acc[2 * cc + 1] += v.y * wgt;
    }
  }
  if (l == 0) {
    float ws = di * di;
#pragma unroll
    for (int cc = 0; cc < NC; ++cc) acc[cc] += h2[(size_t)i * NC + cc] * ws;
  }
#pragma unroll
  for (int cc = 0; cc < NC; ++cc) {
#pragma unroll
    for (int m = 1; m < 64; m <<= 1) acc[cc] += __shfl_xor(acc[cc], m, 64);
  }
  if (l == 0) {
    float v[NC];
    float mx = -1e30f;
#pragma unroll
    for (int cc = 0; cc < NC; ++cc) {
      v[cc] = acc[cc] + b2[cc];
      mx = fmaxf(mx, v[cc]);
    }
    float s = 0.f;
#pragma unroll
    for (int cc = 0; cc < NC; ++cc) s += expf(v[cc] - mx);
    float lse = mx + logf(s);
#pragma unroll
    for (int cc = 0; cc < NC; ++cc) out[(size_t)i * NC + cc] = v[cc] - lse;
  }
}

extern "C" void kernel_launch(void* const* d_in, const int* in_sizes, int n_in,
                              void* d_out, int out_size, void* d_ws, size_t ws_size,
                              hipStream_t stream) {
  (void)in_sizes; (void)n_in; (void)out_size; (void)ws_size;
  const float* x  = (const float*)d_in[0];
  const int*   ei = (const int*)d_in[1];
  const float* W1 = (const float*)d_in[2];
  const float* b1 = (const float*)d_in[3];
  const float* W2 = (const float*)d_in[4];
  const float* b2 = (const float*)d_in[5];
  float* out = (float*)d_out;
  char* ws = (char*)d_ws;

  unsigned short* w1t = (unsigned short*)(ws);              //  4,194,304 B
  unsigned short* h1b = (unsigned short*)(ws + 4194304);    // 20,480,000 B
  float* h2   = (float*)(ws + 24674304);                    //    800,000 B
  int*   deg  = (int*)(ws + 25474304);                      //     80,000 B
  float* dinv = (float*)(ws + 25554304);                    //     80,000 B
  int*   csr  = (int*)(ws + 25634304);                      // 10,240,000 B -> end 35,874,304

  const int* srcp = ei;
  const int* dstp = ei + EE;

  hipMemsetAsync(deg, 0, NN * sizeof(int), stream);
  scatk<<<(EE + 255) / 256, 256, 0, stream>>>(srcp, dstp, deg, csr);
  dinvk<<<(NN + 255) / 256, 256, 0, stream>>>(deg, dinv);
  transk<<<dim3(16, 128), 256, 0, stream>>>(W1, w1t);
  gemm1<<<314 * 4, 256, 0, stream>>>(x, w1t, h1b);
  sgk<<<NN, 128, 0, stream>>>(h1b, deg, csr, dinv, b1, W2, h2);
  spmm2<<<NN, 64, 0, stream>>>(h2, deg, csr, dinv, b2, out);
}